// Round 2
// baseline (444.723 us; speedup 1.0000x reference)
//
#include <hip/hip_runtime.h>
#include <hip/hip_bf16.h>
#include <stdint.h>

typedef __attribute__((ext_vector_type(8))) short short8;
typedef __attribute__((ext_vector_type(4))) float floatx4;

// ---- problem constants ----
constexpr int TD    = 1024;   // token dim
constexpr int E3    = 1536;   // 3*inner
constexpr int INNER = 512;
constexpr int NW    = 512;    // windows
constexpr int M_    = NW * 64; // 32768 tokens

// K-order permutation: reference d = p1*256 + p2*64 + c  <->  d' = c*16 + p1*4 + p2

// ---- workspace layout (bytes) ----
constexpr size_t OFF_TOKA = 0;                                 // tokens bf16 [M, 1024]; oattn aliases later
constexpr size_t OFF_QKV  = (size_t)M_ * TD * 2;               // qkv bf16 [M, 1536]
constexpr size_t OFF_WQT  = OFF_QKV + (size_t)M_ * E3 * 2;     // w_qkv^T bf16 [1536, 1024]
constexpr size_t OFF_WOT  = OFF_WQT + (size_t)E3 * TD * 2;     // w_out^T bf16 [1024, 512]
constexpr size_t OFF_BO   = OFF_WOT + (size_t)TD * INNER * 2;  // bias' fp32 [1024]
constexpr size_t WS_NEED  = OFF_BO + TD * 4;

__device__ __forceinline__ void gl_lds16(const void* g, void* l) {
  __builtin_amdgcn_global_load_lds(
      (const __attribute__((address_space(1))) void*)g,
      (__attribute__((address_space(3))) void*)l, 16, 0, 0);
}

// ---- patchify: x [8,64,256,256] -> tokens bf16 [M, 1024] in d' order ----
__global__ __launch_bounds__(256) void k_patchify(const float* __restrict__ x,
                                                  __hip_bfloat16* __restrict__ tokA) {
  __shared__ __hip_bfloat16 tok[8][1032];
  const int bid = blockIdx.x;
  const int n = bid >> 3, i = bid & 7;
  const int b = n >> 6, h1 = (n >> 3) & 7, w1 = n & 7;
  const int tid = threadIdx.x;
  for (int it = 0; it < 8; ++it) {
    int idx = it * 256 + tid;
    int w4 = idx & 7, p1 = (idx >> 3) & 3, c = idx >> 5;
    int h = h1 * 32 + i * 4 + p1;
    const float4 v = *(const float4*)&x[(((b * 64 + c) * 256 + h) * 256 + w1 * 32 + w4 * 4)];
    __hip_bfloat16* dst = &tok[w4][c * 16 + p1 * 4];
    dst[0] = __float2bfloat16(v.x);
    dst[1] = __float2bfloat16(v.y);
    dst[2] = __float2bfloat16(v.z);
    dst[3] = __float2bfloat16(v.w);
  }
  __syncthreads();
  for (int it = 0; it < 4; ++it) {
    int idx = it * 256 + tid;
    int ch = idx & 127, j = idx >> 7;
    uint4 v = *(const uint4*)&tok[j][ch * 8];
    *(uint4*)&tokA[(size_t)(n * 64 + i * 8 + j) * 1024 + ch * 8] = v;
  }
}

// ---- w_qkv [1024 d][1536 e] fp32 -> wqT bf16 [1536 e][1024 d'] ----
__global__ __launch_bounds__(256) void k_perm_wqkv(const float* __restrict__ wqkv,
                                                   __hip_bfloat16* __restrict__ wqT) {
  __shared__ __hip_bfloat16 wt[16][1032];
  const int e0 = blockIdx.x * 16, tid = threadIdx.x;
  for (int it = 0; it < 64; ++it) {
    int idx = it * 256 + tid;
    int e = idx & 15, d = idx >> 4;
    float v = wqkv[d * 1536 + e0 + e];
    int p1 = d >> 8, p2 = (d >> 6) & 3, c = d & 63;
    wt[e][c * 16 + p1 * 4 + p2] = __float2bfloat16(v);
  }
  __syncthreads();
  for (int it = 0; it < 8; ++it) {
    int idx = it * 256 + tid;
    int ch = idx & 127, e = idx >> 7;
    uint4 v = *(const uint4*)&wt[e][ch * 8];
    *(uint4*)&wqT[(size_t)(e0 + e) * 1024 + ch * 8] = v;
  }
}

// ---- w_out [512 e][1024 d] fp32 -> woT bf16 [1024 d'][512 e] ----
__global__ __launch_bounds__(256) void k_perm_wout(const float* __restrict__ wout,
                                                   __hip_bfloat16* __restrict__ woT) {
  __shared__ __hip_bfloat16 wt[16][1032];
  const int e0 = blockIdx.x * 16, tid = threadIdx.x;
  for (int it = 0; it < 64; ++it) {
    int idx = it * 256 + tid;
    int d = idx & 1023, e = idx >> 10;
    float v = wout[(e0 + e) * 1024 + d];
    int p1 = d >> 8, p2 = (d >> 6) & 3, c = d & 63;
    wt[e][c * 16 + p1 * 4 + p2] = __float2bfloat16(v);
  }
  __syncthreads();
  for (int it = 0; it < 64; ++it) {
    int idx = it * 256 + tid;
    int e = idx & 15, dp = idx >> 4;
    woT[(size_t)dp * 512 + e0 + e] = wt[e][dp];
  }
}

__global__ __launch_bounds__(256) void k_perm_bias(const float* __restrict__ bout,
                                                   float* __restrict__ boP) {
  int dp = blockIdx.x * 256 + threadIdx.x;
  int c = dp >> 4, p1 = (dp >> 2) & 3, p2 = dp & 3;
  boP[dp] = bout[p1 * 256 + p2 * 64 + c];
}

// ============================================================================
// 256x256 8-phase GEMM core with ONE-PHASE REGISTER PREFETCH.
//   BM=BN=256, BK=64, 512 threads = 8 waves (2M x 4N), LDS 128 KiB dbuf.
//   Per phase: {prefetch next phase's A-frags (+B at Q0 tops) | stage 1
//   half-tile gl_lds | barrier | 16 MFMA on PREVIOUS phase's frags | vmcnt |
//   barrier}. The fragment ds_reads drain on the LDS pipe DURING the 620-cyc
//   MFMA cluster (compiler emits counted lgkmcnt) -> LDS/MFMA overlap.
//   Stage schedule per iter i (tiles 2i,2i+1 computed; t1=2i+1,t2=2i+2,t3=2i+3):
//     ph1:A1(t1,b1) ph2:B0(t2,b0) ph3:B1(t2,b0) ph4:A0(t2,b0)
//     ph5:A1(t2,b0) ph6:B0(t3,b1) ph7:B1(t3,b1) ph8:A0(t3,b1)
//   Waits: vmcnt(6) at ph1,3,5,7 (verified: every staged region lands >=1
//   barrier before its first ds_read, 6 loads = 3 phases always in flight).
//   B-frags read at Q0-phase tops (ph1/ph5) into a single bf set; A-frags
//   double-buffered af[2] alternating per phase.
// ============================================================================
template<int K>
__device__ __forceinline__ void gemm256_acc(
    const __hip_bfloat16* __restrict__ A,
    const __hip_bfloat16* __restrict__ Bt,
    int m0, int n0, int tid,
    __hip_bfloat16 (*As)[256][64], __hip_bfloat16 (*Bs)[256][64],
    floatx4 (&acc)[8][4])
{
  const int lane = tid & 63, wid = tid >> 6;
  const int wm = wid >> 2, wn = wid & 3;
  const int l15 = lane & 15, quad = lane >> 4;

  const int rl8 = tid >> 3;
  const int ch0 = (tid & 7) ^ (rl8 & 7);       // pre-swizzled global chunk
  const __hip_bfloat16* Abase = A  + (size_t)(m0 + rl8) * K + ch0 * 8;
  const __hip_bfloat16* Bbase = Bt + (size_t)(n0 + rl8) * K + ch0 * 8;

  // stage one B half-tile (rows half*128..+128) of K-tile `tile` into Bs[buf]
  auto stageB = [&](int tile, int half, int buf) {
#pragma unroll
    for (int j = 0; j < 2; ++j)
      gl_lds16(Bbase + (size_t)(half * 128 + j * 64) * K + tile * 64,
               (char*)&Bs[buf][0][0] + half * 16384 + (j * 512 + tid) * 16);
  };
  // stage one A quad-chunk (rows chunk*64..+64 and 128+chunk*64..+64)
  auto stageA = [&](int tile, int chunk, int buf) {
#pragma unroll
    for (int j = 0; j < 2; ++j)
      gl_lds16(Abase + (size_t)(j * 128 + chunk * 64) * K + tile * 64,
               (char*)&As[buf][0][0] + j * 16384 + chunk * 8192 + tid * 16);
  };

  short8 af[2][2][2];   // [set][m2][kh] — A frags, set alternates per phase
  short8 bf[4][2];      // [n][kh]      — B frags for current group

#define VM6 asm volatile("s_waitcnt vmcnt(6)" ::: "memory")
#define VM0 asm volatile("s_waitcnt vmcnt(0)" ::: "memory")

// CS: current af set; QC: current Q (m-frags {2QC,2QC+1}); BUFC: current buf;
// LDB: load bf from BUFC at top (Q0 phases); PFAF: prefetch af[CS^1] for
// (QN,BUFN); STAGE: gl_lds issue; VMW: vmcnt before 2nd barrier.
#define PH(CS, QC, BUFC, LDB, QN, BUFN, PFAF, STAGE, VMW)                         \
  do {                                                                            \
    if (LDB) {                                                                    \
      _Pragma("unroll") for (int n = 0; n < 4; ++n) {                             \
        const int rb = wn * 64 + n * 16 + l15;                                    \
        _Pragma("unroll") for (int kh = 0; kh < 2; ++kh)                          \
          bf[n][kh] = *(const short8*)&Bs[BUFC][rb][((kh * 4 + quad) ^ (rb & 7)) * 8]; \
      }                                                                           \
    }                                                                             \
    if (PFAF) {                                                                   \
      _Pragma("unroll") for (int m2 = 0; m2 < 2; ++m2) {                          \
        const int r = wm * 128 + (2 * (QN) + m2) * 16 + l15;                      \
        _Pragma("unroll") for (int kh = 0; kh < 2; ++kh)                          \
          af[(CS) ^ 1][m2][kh] = *(const short8*)&As[BUFN][r][((kh * 4 + quad) ^ (r & 7)) * 8]; \
      }                                                                           \
    }                                                                             \
    STAGE;                                                                        \
    __builtin_amdgcn_s_barrier();                                                 \
    __builtin_amdgcn_sched_barrier(0);                                            \
    __builtin_amdgcn_s_setprio(1);                                                \
    _Pragma("unroll") for (int kh = 0; kh < 2; ++kh)                              \
      _Pragma("unroll") for (int m2 = 0; m2 < 2; ++m2)                            \
        _Pragma("unroll") for (int n = 0; n < 4; ++n)                             \
          acc[2 * (QC) + m2][n] = __builtin_amdgcn_mfma_f32_16x16x32_bf16(        \
              af[CS][m2][kh], bf[n][kh], acc[2 * (QC) + m2][n], 0, 0, 0);         \
    __builtin_amdgcn_s_setprio(0);                                                \
    __builtin_amdgcn_sched_barrier(0);                                            \
    VMW;                                                                          \
    __builtin_amdgcn_s_barrier();                                                 \
    __builtin_amdgcn_sched_barrier(0);                                            \
  } while (0)

  // ---- prologue: tile0 complete + tile1 {B0,B1,A0}; 6 loads left in flight
  stageB(0, 0, 0); stageB(0, 1, 0); stageA(0, 0, 0); stageA(0, 1, 0);
  stageB(1, 0, 1); stageB(1, 1, 1); stageA(1, 0, 1);
  VM6;                                   // oldest 8 of 14 done -> tile0 landed
  __builtin_amdgcn_s_barrier();
  __builtin_amdgcn_sched_barrier(0);
  // preload Q0 A-frags of tile0 into set 0
#pragma unroll
  for (int m2 = 0; m2 < 2; ++m2) {
    const int r = wm * 128 + m2 * 16 + l15;
#pragma unroll
    for (int kh = 0; kh < 2; ++kh)
      af[0][m2][kh] = *(const short8*)&As[0][r][((kh * 4 + quad) ^ (r & 7)) * 8];
  }

  constexpr int NIT = K / 128;   // 2 K-tiles per iteration
#pragma unroll 1
  for (int i = 0; i < NIT - 1; ++i) {
    const int t1 = 2 * i + 1, t2 = 2 * i + 2, t3 = 2 * i + 3;
    PH(0, 0, 0, 1, 1, 0, 1, stageA(t1, 1, 1), VM6);
    PH(1, 1, 0, 0, 2, 0, 1, stageB(t2, 0, 0), );
    PH(0, 2, 0, 0, 3, 0, 1, stageB(t2, 1, 0), VM6);
    PH(1, 3, 0, 0, 0, 1, 1, stageA(t2, 0, 0), );
    PH(0, 0, 1, 1, 1, 1, 1, stageA(t2, 1, 0), VM6);
    PH(1, 1, 1, 0, 2, 1, 1, stageB(t3, 0, 1), );
    PH(0, 2, 1, 0, 3, 1, 1, stageB(t3, 1, 1), VM6);
    PH(1, 3, 1, 0, 0, 0, 1, stageA(t3, 0, 1), );
  }
  // ---- epilogue pair: tiles 2*NIT-2 (buf0), 2*NIT-1 (buf1)
  {
    const int tE = 2 * NIT - 1;
    PH(0, 0, 0, 1, 1, 0, 1, stageA(tE, 1, 1), VM6);
    PH(1, 1, 0, 0, 2, 0, 1, , );
    PH(0, 2, 0, 0, 3, 0, 1, , VM0);
    PH(1, 3, 0, 0, 0, 1, 1, , );
    PH(0, 0, 1, 1, 1, 1, 1, , );
    PH(1, 1, 1, 0, 2, 1, 1, , );
    PH(0, 2, 1, 0, 3, 1, 1, , );
    PH(1, 3, 1, 0, 0, 0, 0, , );
  }
#undef PH
#undef VM6
#undef VM0
}

// ---- GEMM1: tokens [M,1024] x wqT^T -> qkv bf16 [M,1536] ----
__global__ __launch_bounds__(512, 2) void k_gemm_qkv(const __hip_bfloat16* __restrict__ A,
                                                     const __hip_bfloat16* __restrict__ Bt,
                                                     __hip_bfloat16* __restrict__ Cmat) {
  __shared__ __hip_bfloat16 As[2][256][64];
  __shared__ __hip_bfloat16 Bs[2][256][64];
  const int tid = threadIdx.x;
  const int bid = blockIdx.x;
  const int swz = (bid & 7) * 96 + (bid >> 3);   // 768 blocks, bijective XCD swizzle
  const int n0 = (swz % 6) * 256, m0 = (swz / 6) * 256;  // n-major: A-tile L2 reuse
  floatx4 acc[8][4] = {};
  gemm256_acc<1024>(A, Bt, m0, n0, tid, As, Bs, acc);
  const int lane = tid & 63, wid = tid >> 6;
  const int wm = wid >> 2, wn = wid & 3;
  const int l15 = lane & 15, quad = lane >> 4;
#pragma unroll
  for (int mt = 0; mt < 8; ++mt)
#pragma unroll
    for (int nt = 0; nt < 4; ++nt) {
      const int col = n0 + wn * 64 + nt * 16 + l15;
#pragma unroll
      for (int r = 0; r < 4; ++r) {
        const int row = m0 + wm * 128 + mt * 16 + quad * 4 + r;
        Cmat[(size_t)row * 1536 + col] = __float2bfloat16(acc[mt][nt][r]);
      }
    }
}

// ---- attention: one block per (window, head); swizzled Q/K, bank-clean V transpose ----
__global__ __launch_bounds__(256) void k_attn(const __hip_bfloat16* __restrict__ qkv,
                                              __hip_bfloat16* __restrict__ oattn) {
  __shared__ __hip_bfloat16 Qs[64 * 64];   // [t][dh] swizzled chunks
  __shared__ __hip_bfloat16 Ks[64 * 64];   // [t][dh] swizzled chunks
  __shared__ __hip_bfloat16 Vt[64 * 72];   // [dh][t] padded
  __shared__ __hip_bfloat16 Ps[64 * 72];   // [t][t'] padded; first reused as swizzled Vs[64*64]
  const int win = blockIdx.x, head = blockIdx.y;
  const int tid = threadIdx.x, lane = tid & 63, wid = tid >> 6;
  const int l15 = lane & 15, quad = lane >> 4;
  const int sx = l15 & 7;
  const size_t base = (size_t)win * 64 * 1536 + head * 64;
  for (int l = 0; l < 2; ++l) {
    int idx = l * 256 + tid;
    int t = idx >> 3, ch = idx & 7;
    const size_t rowb = base + (size_t)t * 1536 + ch * 8;
    uint4 q = *(const uint4*)&qkv[rowb];
    uint4 k = *(const uint4*)&qkv[rowb + 512];
    uint4 v = *(const uint4*)&qkv[rowb + 1024];
    const int pos = (ch ^ (t & 7)) * 8;
    *(uint4*)&Qs[t * 64 + pos] = q;
    *(uint4*)&Ks[t * 64 + pos] = k;
    *(uint4*)&Ps[t * 64 + pos] = v;       // Vs staging (swizzled), Ps not yet live
  }
  __syncthreads();
  // transpose V: Vs (swizzled [t][dh]) -> Vt [dh][t]
  {
    const int t = tid & 63, w = tid >> 6;
#pragma unroll
    for (int jn = 0; jn < 2; ++jn) {
      int j = w * 2 + jn;                                  // dh chunk
      short8 v = *(const short8*)&Ps[t * 64 + ((j ^ (t & 7)) * 8)];
#pragma unroll
      for (int jj = 0; jj < 8; ++jj) Vt[(j * 8 + jj) * 72 + t] = ((__hip_bfloat16*)&v)[jj];
    }
  }
  __syncthreads();   // Vs reads done; Ps may now be overwritten by softmax
  // S = Q K^T * scale
  floatx4 sacc[4] = {};
#pragma unroll
  for (int kk = 0; kk < 64; kk += 32) {
    const int pos = (((kk >> 3) + quad) ^ sx) * 8;
    short8 aq = *(const short8*)&Qs[(wid * 16 + l15) * 64 + pos];
#pragma unroll
    for (int ct = 0; ct < 4; ++ct) {
      short8 bk = *(const short8*)&Ks[(ct * 16 + l15) * 64 + pos];
      sacc[ct] = __builtin_amdgcn_mfma_f32_16x16x32_bf16(aq, bk, sacc[ct], 0, 0, 0);
    }
  }
#pragma unroll
  for (int ct = 0; ct < 4; ++ct)
#pragma unroll
    for (int r = 0; r < 4; ++r) sacc[ct][r] = sacc[ct][r] * 0.125f;
  // softmax per row
#pragma unroll
  for (int r = 0; r < 4; ++r) {
    float m = fmaxf(fmaxf(sacc[0][r], sacc[1][r]), fmaxf(sacc[2][r], sacc[3][r]));
    m = fmaxf(m, __shfl_xor(m, 1));
    m = fmaxf(m, __shfl_xor(m, 2));
    m = fmaxf(m, __shfl_xor(m, 4));
    m = fmaxf(m, __shfl_xor(m, 8));
    float ev[4]; float s0 = 0.f;
#pragma unroll
    for (int ct = 0; ct < 4; ++ct) { ev[ct] = __expf(sacc[ct][r] - m); s0 += ev[ct]; }
    s0 += __shfl_xor(s0, 1);
    s0 += __shfl_xor(s0, 2);
    s0 += __shfl_xor(s0, 4);
    s0 += __shfl_xor(s0, 8);
    float inv = 1.0f / s0;
    int row = wid * 16 + quad * 4 + r;
#pragma unroll
    for (int ct = 0; ct < 4; ++ct)
      Ps[row * 72 + ct * 16 + l15] = __float2bfloat16(ev[ct] * inv);
  }
  __syncthreads();
  // O = P V
  floatx4 oacc[4] = {};
#pragma unroll
  for (int kk = 0; kk < 64; kk += 32) {
    const int q8 = quad * 8;
    short8 ap = *(const short8*)&Ps[(wid * 16 + l15) * 72 + kk + q8];
#pragma unroll
    for (int nt = 0; nt < 4; ++nt) {
      short8 bv = *(const short8*)&Vt[(nt * 16 + l15) * 72 + kk + q8];
      oacc[nt] = __builtin_amdgcn_mfma_f32_16x16x32_bf16(ap, bv, oacc[nt], 0, 0, 0);
    }
  }
#pragma unroll
  for (int nt = 0; nt < 4; ++nt) {
    int dh = nt * 16 + l15;
#pragma unroll
    for (int r = 0; r < 4; ++r) {
      int t = wid * 16 + quad * 4 + r;
      oattn[((size_t)win * 64 + t) * 512 + head * 64 + dh] = __float2bfloat16(oacc[nt][r]);
    }
  }
}

// ---- GEMM2 + bias + un-patchify scatter ----
__global__ __launch_bounds__(512, 2) void k_gemm_out(const __hip_bfloat16* __restrict__ A,
                                                     const __hip_bfloat16* __restrict__ Bt,
                                                     const float* __restrict__ bias,
                                                     float* __restrict__ out) {
  __shared__ __hip_bfloat16 As[2][256][64];
  __shared__ __hip_bfloat16 Bs[2][256][64];
  const int tid = threadIdx.x;
  const int bid = blockIdx.x;
  const int swz = (bid & 7) * 64 + (bid >> 3);   // 512 blocks
  const int n0 = (swz & 3) * 256, m0 = (swz >> 2) * 256;
  floatx4 acc[8][4] = {};
  gemm256_acc<512>(A, Bt, m0, n0, tid, As, Bs, acc);
  const int lane = tid & 63, wid = tid >> 6;
  const int wm = wid >> 2, wn = wid & 3;
  const int l15 = lane & 15, quad = lane >> 4;
#pragma unroll
  for (int nt = 0; nt < 4; ++nt) {
    const int dp = n0 + wn * 64 + nt * 16 + l15;
    const float bv = bias[dp];
    const int c = dp >> 4, p1 = (dp >> 2) & 3, p2 = dp & 3;
#pragma unroll
    for (int mt = 0; mt < 8; ++mt)
#pragma unroll
      for (int r = 0; r < 4; ++r) {
        const int m = m0 + wm * 128 + mt * 16 + quad * 4 + r;
        const int win = m >> 6, t = m & 63;
        const int i = t >> 3, j = t & 7;
        const int b = win >> 6, h1 = (win >> 3) & 7, w1 = win & 7;
        const int h = h1 * 32 + i * 4 + p1, w = w1 * 32 + j * 4 + p2;
        out[((b * 64 + c) * 256 + h) * 256 + w] = acc[mt][nt][r] + bv;
      }
  }
}

extern "C" void kernel_launch(void* const* d_in, const int* in_sizes, int n_in,
                              void* d_out, int out_size, void* d_ws, size_t ws_size,
                              hipStream_t stream) {
  const float* x    = (const float*)d_in[0];
  const float* wqkv = (const float*)d_in[1];
  const float* wout = (const float*)d_in[2];
  const float* bout = (const float*)d_in[3];
  float* out = (float*)d_out;
  char* ws = (char*)d_ws;
  if (ws_size < WS_NEED) return;

  __hip_bfloat16* tokA  = (__hip_bfloat16*)(ws + OFF_TOKA);
  __hip_bfloat16* oattn = (__hip_bfloat16*)(ws + OFF_TOKA);  // aliases tokA (dead after GEMM1)
  __hip_bfloat16* qkv   = (__hip_bfloat16*)(ws + OFF_QKV);
  __hip_bfloat16* wqT   = (__hip_bfloat16*)(ws + OFF_WQT);
  __hip_bfloat16* woT   = (__hip_bfloat16*)(ws + OFF_WOT);
  float* boP = (float*)(ws + OFF_BO);

  k_perm_wqkv<<<96, 256, 0, stream>>>(wqkv, wqT);
  k_perm_wout<<<32, 256, 0, stream>>>(wout, woT);
  k_perm_bias<<<4, 256, 0, stream>>>(bout, boP);
  k_patchify<<<4096, 256, 0, stream>>>(x, tokA);
  k_gemm_qkv<<<768, 512, 0, stream>>>(tokA, wqT, qkv);
  k_attn<<<dim3(512, 8), 256, 0, stream>>>(qkv, oattn);
  k_gemm_out<<<512, 512, 0, stream>>>(oattn, woT, boP, out);
}

// Round 3
// 440.709 us; speedup vs baseline: 1.0091x; 1.0091x over previous
//
#include <hip/hip_runtime.h>
#include <hip/hip_bf16.h>
#include <stdint.h>

typedef __attribute__((ext_vector_type(8))) short short8;
typedef __attribute__((ext_vector_type(4))) float floatx4;

// ---- problem constants ----
constexpr int TD    = 1024;   // token dim
constexpr int E3    = 1536;   // 3*inner
constexpr int INNER = 512;
constexpr int NW    = 512;    // windows
constexpr int M_    = NW * 64; // 32768 tokens

// K-order permutation: reference d = p1*256 + p2*64 + c  <->  d' = c*16 + p1*4 + p2

// ---- workspace layout (bytes) ----
constexpr size_t OFF_TOKA = 0;                                 // tokens bf16 [M, 1024]; oattn aliases later
constexpr size_t OFF_QKV  = (size_t)M_ * TD * 2;               // qkv bf16 [M, 1536]
constexpr size_t OFF_WQT  = OFF_QKV + (size_t)M_ * E3 * 2;     // w_qkv^T bf16 [1536, 1024]
constexpr size_t OFF_WOT  = OFF_WQT + (size_t)E3 * TD * 2;     // w_out^T bf16 [1024, 512]
constexpr size_t OFF_BO   = OFF_WOT + (size_t)TD * INNER * 2;  // bias' fp32 [1024]
constexpr size_t WS_NEED  = OFF_BO + TD * 4;

__device__ __forceinline__ void gl_lds16(const void* g, void* l) {
  __builtin_amdgcn_global_load_lds(
      (const __attribute__((address_space(1))) void*)g,
      (__attribute__((address_space(3))) void*)l, 16, 0, 0);
}

// ---- patchify: x [8,64,256,256] -> tokens bf16 [M, 1024] in d' order ----
__global__ __launch_bounds__(256) void k_patchify(const float* __restrict__ x,
                                                  __hip_bfloat16* __restrict__ tokA) {
  __shared__ __hip_bfloat16 tok[8][1032];
  const int bid = blockIdx.x;
  const int n = bid >> 3, i = bid & 7;
  const int b = n >> 6, h1 = (n >> 3) & 7, w1 = n & 7;
  const int tid = threadIdx.x;
  for (int it = 0; it < 8; ++it) {
    int idx = it * 256 + tid;
    int w4 = idx & 7, p1 = (idx >> 3) & 3, c = idx >> 5;
    int h = h1 * 32 + i * 4 + p1;
    const float4 v = *(const float4*)&x[(((b * 64 + c) * 256 + h) * 256 + w1 * 32 + w4 * 4)];
    __hip_bfloat16* dst = &tok[w4][c * 16 + p1 * 4];
    dst[0] = __float2bfloat16(v.x);
    dst[1] = __float2bfloat16(v.y);
    dst[2] = __float2bfloat16(v.z);
    dst[3] = __float2bfloat16(v.w);
  }
  __syncthreads();
  for (int it = 0; it < 4; ++it) {
    int idx = it * 256 + tid;
    int ch = idx & 127, j = idx >> 7;
    uint4 v = *(const uint4*)&tok[j][ch * 8];
    *(uint4*)&tokA[(size_t)(n * 64 + i * 8 + j) * 1024 + ch * 8] = v;
  }
}

// ---- w_qkv [1024 d][1536 e] fp32 -> wqT bf16 [1536 e][1024 d'] ----
// grid (96, 2): bx = 16-wide e stripe, by = d half (p1 pair) -> 192 blocks
__global__ __launch_bounds__(256) void k_perm_wqkv(const float* __restrict__ wqkv,
                                                   __hip_bfloat16* __restrict__ wqT) {
  __shared__ __hip_bfloat16 wt[16][520];
  const int e0 = blockIdx.x * 16, by = blockIdx.y, tid = threadIdx.x;
  for (int it = 0; it < 32; ++it) {
    int idx = it * 256 + tid;
    int e = idx & 15, dl = idx >> 4;          // dl in [0,512)
    int d = by * 512 + dl;
    float v = wqkv[d * 1536 + e0 + e];
    int c = d & 63, off = (d >> 6) & 7;       // d' = c*16 + by*8 + off
    wt[e][c * 8 + off] = __float2bfloat16(v);
  }
  __syncthreads();
  for (int it = 0; it < 4; ++it) {
    int idx = it * 256 + tid;
    int ch = idx & 63, e = idx >> 6;
    uint4 v = *(const uint4*)&wt[e][ch * 8];
    *(uint4*)&wqT[(size_t)(e0 + e) * 1024 + ch * 16 + by * 8] = v;
  }
}

// ---- w_out [512 e][1024 d] fp32 -> woT bf16 [1024 d'][512 e] ----
// grid (128, 2): bx = 4-wide e stripe, by = d half -> 256 blocks
__global__ __launch_bounds__(256) void k_perm_wout(const float* __restrict__ wout,
                                                   __hip_bfloat16* __restrict__ woT) {
  __shared__ __hip_bfloat16 wt[4][520];
  const int e0 = blockIdx.x * 4, by = blockIdx.y, tid = threadIdx.x;
  for (int it = 0; it < 8; ++it) {
    int idx = it * 256 + tid;
    int dl = idx & 511, e = idx >> 9;
    int d = by * 512 + dl;
    float v = wout[(e0 + e) * 1024 + d];
    int c = d & 63, off = (d >> 6) & 7;
    wt[e][c * 8 + off] = __float2bfloat16(v);
  }
  __syncthreads();
  for (int it = 0; it < 8; ++it) {
    int idx = it * 256 + tid;
    int e = idx & 3, sl = idx >> 2;           // sl in [0,512)
    int c = sl >> 3, off = sl & 7;
    int dp = c * 16 + by * 8 + off;
    woT[(size_t)dp * 512 + e0 + e] = wt[e][sl];
  }
}

__global__ __launch_bounds__(256) void k_perm_bias(const float* __restrict__ bout,
                                                   float* __restrict__ boP) {
  int dp = blockIdx.x * 256 + threadIdx.x;
  int c = dp >> 4, p1 = (dp >> 2) & 3, p2 = dp & 3;
  boP[dp] = bout[p1 * 256 + p2 * 64 + c];
}

// ============================================================================
// 256x256 8-phase GEMM core, 1-phase register prefetch + EXPLICIT COUNTED
// lgkmcnt(4) per phase.
//   Q0 phases read bf FIRST (8 ds_read_b128), then the 4 af-prefetch reads;
//   lgkmcnt(4) after the barrier allows only the 4 af-prefetch reads to stay
//   outstanding -> bf and af-current provably drained, and the 4 new reads
//   drain on the LDS pipe DURING the 620-cyc MFMA cluster.
//   Stage schedule per iter (t1=2i+1, t2=2i+2, t3=2i+3):
//     ph1:A1(t1,b1) ph2:B0(t2,b0) ph3:B1(t2,b0) ph4:A0(t2,b0)
//     ph5:A1(t2,b0) ph6:B0(t3,b1) ph7:B1(t3,b1) ph8:A0(t3,b1)
//   vmcnt(6) at ends of ph1,3,5,7 (deadline-verified: every staged region
//   lands >=1 barrier before its first ds_read; 3 stages always in flight).
// ============================================================================
template<int K>
__device__ __forceinline__ void gemm256_acc(
    const __hip_bfloat16* __restrict__ A,
    const __hip_bfloat16* __restrict__ Bt,
    int m0, int n0, int tid,
    __hip_bfloat16 (*As)[256][64], __hip_bfloat16 (*Bs)[256][64],
    floatx4 (&acc)[8][4])
{
  const int lane = tid & 63, wid = tid >> 6;
  const int wm = wid >> 2, wn = wid & 3;
  const int l15 = lane & 15, quad = lane >> 4;

  const int rl8 = tid >> 3;
  const int ch0 = (tid & 7) ^ (rl8 & 7);       // pre-swizzled global chunk
  const __hip_bfloat16* Abase = A  + (size_t)(m0 + rl8) * K + ch0 * 8;
  const __hip_bfloat16* Bbase = Bt + (size_t)(n0 + rl8) * K + ch0 * 8;

  auto stageB = [&](int tile, int half, int buf) {
#pragma unroll
    for (int j = 0; j < 2; ++j)
      gl_lds16(Bbase + (size_t)(half * 128 + j * 64) * K + tile * 64,
               (char*)&Bs[buf][0][0] + half * 16384 + (j * 512 + tid) * 16);
  };
  auto stageA = [&](int tile, int chunk, int buf) {
#pragma unroll
    for (int j = 0; j < 2; ++j)
      gl_lds16(Abase + (size_t)(j * 128 + chunk * 64) * K + tile * 64,
               (char*)&As[buf][0][0] + j * 16384 + chunk * 8192 + tid * 16);
  };

  short8 af[2][2][2];   // [set][m2][kh] — A frags, set alternates per phase
  short8 bf[4][2];      // [n][kh]      — B frags for current 4-phase group

#define VM6 asm volatile("s_waitcnt vmcnt(6)" ::: "memory")
#define VM0 asm volatile("s_waitcnt vmcnt(0)" ::: "memory")
#define LGKM4 do { asm volatile("s_waitcnt lgkmcnt(4)" ::: "memory"); \
                   __builtin_amdgcn_sched_barrier(0); } while (0)
#define LGKM0 do { asm volatile("s_waitcnt lgkmcnt(0)" ::: "memory"); \
                   __builtin_amdgcn_sched_barrier(0); } while (0)

// CS: current af set; QC: current Q; BUFC: current buf; LDB: load bf (Q0);
// QN/BUFN: next phase's af target; PF: do af prefetch; STAGE: gl_lds;
// VMW: vmcnt before 2nd barrier; LG: lgkm wait (LGKM4 normal, LGKM0 last).
#define PH(CS, QC, BUFC, LDB, QN, BUFN, PF, STAGE, VMW, LG)                       \
  do {                                                                            \
    if (LDB) {  /* bf FIRST so lgkmcnt(4) covers it */                            \
      _Pragma("unroll") for (int n = 0; n < 4; ++n) {                             \
        const int rb = wn * 64 + n * 16 + l15;                                    \
        _Pragma("unroll") for (int kh = 0; kh < 2; ++kh)                          \
          bf[n][kh] = *(const short8*)&Bs[BUFC][rb][((kh * 4 + quad) ^ (rb & 7)) * 8]; \
      }                                                                           \
    }                                                                             \
    if (PF) {                                                                     \
      _Pragma("unroll") for (int m2 = 0; m2 < 2; ++m2) {                          \
        const int r = wm * 128 + (2 * (QN) + m2) * 16 + l15;                      \
        _Pragma("unroll") for (int kh = 0; kh < 2; ++kh)                          \
          af[(CS) ^ 1][m2][kh] = *(const short8*)&As[BUFN][r][((kh * 4 + quad) ^ (r & 7)) * 8]; \
      }                                                                           \
    }                                                                             \
    STAGE;                                                                        \
    __builtin_amdgcn_sched_barrier(0);                                            \
    __builtin_amdgcn_s_barrier();                                                 \
    LG;                                                                           \
    __builtin_amdgcn_s_setprio(1);                                                \
    _Pragma("unroll") for (int kh = 0; kh < 2; ++kh)                              \
      _Pragma("unroll") for (int m2 = 0; m2 < 2; ++m2)                            \
        _Pragma("unroll") for (int n = 0; n < 4; ++n)                             \
          acc[2 * (QC) + m2][n] = __builtin_amdgcn_mfma_f32_16x16x32_bf16(        \
              af[CS][m2][kh], bf[n][kh], acc[2 * (QC) + m2][n], 0, 0, 0);         \
    __builtin_amdgcn_s_setprio(0);                                                \
    __builtin_amdgcn_sched_barrier(0);                                            \
    VMW;                                                                          \
    __builtin_amdgcn_s_barrier();                                                 \
    __builtin_amdgcn_sched_barrier(0);                                            \
  } while (0)

  // ---- prologue: tile0 complete + tile1 {B0,B1,A0}; 6 loads left in flight
  stageB(0, 0, 0); stageB(0, 1, 0); stageA(0, 0, 0); stageA(0, 1, 0);
  stageB(1, 0, 1); stageB(1, 1, 1); stageA(1, 0, 1);
  VM6;                                   // oldest 8 of 14 done -> tile0 landed
  __builtin_amdgcn_s_barrier();
  __builtin_amdgcn_sched_barrier(0);
  // preload Q0 A-frags of tile0 into set 0 (drained by ph1's lgkmcnt(4))
#pragma unroll
  for (int m2 = 0; m2 < 2; ++m2) {
    const int r = wm * 128 + m2 * 16 + l15;
#pragma unroll
    for (int kh = 0; kh < 2; ++kh)
      af[0][m2][kh] = *(const short8*)&As[0][r][((kh * 4 + quad) ^ (r & 7)) * 8];
  }

  constexpr int NIT = K / 128;   // 2 K-tiles per iteration
#pragma unroll 1
  for (int i = 0; i < NIT - 1; ++i) {
    const int t1 = 2 * i + 1, t2 = 2 * i + 2, t3 = 2 * i + 3;
    PH(0, 0, 0, 1, 1, 0, 1, stageA(t1, 1, 1), VM6, LGKM4);
    PH(1, 1, 0, 0, 2, 0, 1, stageB(t2, 0, 0),    , LGKM4);
    PH(0, 2, 0, 0, 3, 0, 1, stageB(t2, 1, 0), VM6, LGKM4);
    PH(1, 3, 0, 0, 0, 1, 1, stageA(t2, 0, 0),    , LGKM4);
    PH(0, 0, 1, 1, 1, 1, 1, stageA(t2, 1, 0), VM6, LGKM4);
    PH(1, 1, 1, 0, 2, 1, 1, stageB(t3, 0, 1),    , LGKM4);
    PH(0, 2, 1, 0, 3, 1, 1, stageB(t3, 1, 1), VM6, LGKM4);
    PH(1, 3, 1, 0, 0, 0, 1, stageA(t3, 0, 1),    , LGKM4);
  }
  // ---- epilogue pair: tiles 2*NIT-2 (buf0), 2*NIT-1 (buf1)
  {
    const int tE = 2 * NIT - 1;
    PH(0, 0, 0, 1, 1, 0, 1, stageA(tE, 1, 1), VM6, LGKM4);
    PH(1, 1, 0, 0, 2, 0, 1, ,    , LGKM4);
    PH(0, 2, 0, 0, 3, 0, 1, , VM0, LGKM4);
    PH(1, 3, 0, 0, 0, 1, 1, ,    , LGKM4);
    PH(0, 0, 1, 1, 1, 1, 1, ,    , LGKM4);
    PH(1, 1, 1, 0, 2, 1, 1, ,    , LGKM4);
    PH(0, 2, 1, 0, 3, 1, 1, ,    , LGKM4);
    PH(1, 3, 1, 0, 0, 0, 0, ,    , LGKM0);
  }
#undef PH
#undef VM6
#undef VM0
#undef LGKM4
#undef LGKM0
}

// ---- GEMM1: tokens [M,1024] x wqT^T -> qkv bf16 [M,1536] ----
// Split into two launches over N (512 + 256 blocks) so other kernels surface
// in the profiler top-5; both are whole multiples of 256 CUs (no tail loss).
__global__ __launch_bounds__(512, 2) void k_gemm_qkv(const __hip_bfloat16* __restrict__ A,
                                                     const __hip_bfloat16* __restrict__ Bt,
                                                     __hip_bfloat16* __restrict__ Cmat,
                                                     int lognb, int nbase) {
  __shared__ __hip_bfloat16 As[2][256][64];
  __shared__ __hip_bfloat16 Bs[2][256][64];
  const int tid = threadIdx.x;
  const int bid = blockIdx.x;
  const int cpx = gridDim.x >> 3;
  const int swz = (bid & 7) * cpx + (bid >> 3);   // bijective XCD swizzle
  const int nb1 = (1 << lognb) - 1;
  const int n0 = nbase + (swz & nb1) * 256, m0 = (swz >> lognb) * 256;
  floatx4 acc[8][4] = {};
  gemm256_acc<1024>(A, Bt, m0, n0, tid, As, Bs, acc);
  const int lane = tid & 63, wid = tid >> 6;
  const int wm = wid >> 2, wn = wid & 3;
  const int l15 = lane & 15, quad = lane >> 4;
#pragma unroll
  for (int mt = 0; mt < 8; ++mt)
#pragma unroll
    for (int nt = 0; nt < 4; ++nt) {
      const int col = n0 + wn * 64 + nt * 16 + l15;
#pragma unroll
      for (int r = 0; r < 4; ++r) {
        const int row = m0 + wm * 128 + mt * 16 + quad * 4 + r;
        Cmat[(size_t)row * 1536 + col] = __float2bfloat16(acc[mt][nt][r]);
      }
    }
}

// ---- attention: one block per (window, head); swizzled Q/K, bank-clean V transpose ----
__global__ __launch_bounds__(256) void k_attn(const __hip_bfloat16* __restrict__ qkv,
                                              __hip_bfloat16* __restrict__ oattn) {
  __shared__ __hip_bfloat16 Qs[64 * 64];   // [t][dh] swizzled chunks
  __shared__ __hip_bfloat16 Ks[64 * 64];   // [t][dh] swizzled chunks
  __shared__ __hip_bfloat16 Vt[64 * 72];   // [dh][t] padded
  __shared__ __hip_bfloat16 Ps[64 * 72];   // [t][t'] padded; first reused as swizzled Vs[64*64]
  const int win = blockIdx.x, head = blockIdx.y;
  const int tid = threadIdx.x, lane = tid & 63, wid = tid >> 6;
  const int l15 = lane & 15, quad = lane >> 4;
  const int sx = l15 & 7;
  const size_t base = (size_t)win * 64 * 1536 + head * 64;
  for (int l = 0; l < 2; ++l) {
    int idx = l * 256 + tid;
    int t = idx >> 3, ch = idx & 7;
    const size_t rowb = base + (size_t)t * 1536 + ch * 8;
    uint4 q = *(const uint4*)&qkv[rowb];
    uint4 k = *(const uint4*)&qkv[rowb + 512];
    uint4 v = *(const uint4*)&qkv[rowb + 1024];
    const int pos = (ch ^ (t & 7)) * 8;
    *(uint4*)&Qs[t * 64 + pos] = q;
    *(uint4*)&Ks[t * 64 + pos] = k;
    *(uint4*)&Ps[t * 64 + pos] = v;       // Vs staging (swizzled), Ps not yet live
  }
  __syncthreads();
  // transpose V: Vs (swizzled [t][dh]) -> Vt [dh][t]
  {
    const int t = tid & 63, w = tid >> 6;
#pragma unroll
    for (int jn = 0; jn < 2; ++jn) {
      int j = w * 2 + jn;                                  // dh chunk
      short8 v = *(const short8*)&Ps[t * 64 + ((j ^ (t & 7)) * 8)];
#pragma unroll
      for (int jj = 0; jj < 8; ++jj) Vt[(j * 8 + jj) * 72 + t] = ((__hip_bfloat16*)&v)[jj];
    }
  }
  __syncthreads();   // Vs reads done; Ps may now be overwritten by softmax
  // S = Q K^T * scale
  floatx4 sacc[4] = {};
#pragma unroll
  for (int kk = 0; kk < 64; kk += 32) {
    const int pos = (((kk >> 3) + quad) ^ sx) * 8;
    short8 aq = *(const short8*)&Qs[(wid * 16 + l15) * 64 + pos];
#pragma unroll
    for (int ct = 0; ct < 4; ++ct) {
      short8 bk = *(const short8*)&Ks[(ct * 16 + l15) * 64 + pos];
      sacc[ct] = __builtin_amdgcn_mfma_f32_16x16x32_bf16(aq, bk, sacc[ct], 0, 0, 0);
    }
  }
#pragma unroll
  for (int ct = 0; ct < 4; ++ct)
#pragma unroll
    for (int r = 0; r < 4; ++r) sacc[ct][r] = sacc[ct][r] * 0.125f;
  // softmax per row
#pragma unroll
  for (int r = 0; r < 4; ++r) {
    float m = fmaxf(fmaxf(sacc[0][r], sacc[1][r]), fmaxf(sacc[2][r], sacc[3][r]));
    m = fmaxf(m, __shfl_xor(m, 1));
    m = fmaxf(m, __shfl_xor(m, 2));
    m = fmaxf(m, __shfl_xor(m, 4));
    m = fmaxf(m, __shfl_xor(m, 8));
    float ev[4]; float s0 = 0.f;
#pragma unroll
    for (int ct = 0; ct < 4; ++ct) { ev[ct] = __expf(sacc[ct][r] - m); s0 += ev[ct]; }
    s0 += __shfl_xor(s0, 1);
    s0 += __shfl_xor(s0, 2);
    s0 += __shfl_xor(s0, 4);
    s0 += __shfl_xor(s0, 8);
    float inv = 1.0f / s0;
    int row = wid * 16 + quad * 4 + r;
#pragma unroll
    for (int ct = 0; ct < 4; ++ct)
      Ps[row * 72 + ct * 16 + l15] = __float2bfloat16(ev[ct] * inv);
  }
  __syncthreads();
  // O = P V
  floatx4 oacc[4] = {};
#pragma unroll
  for (int kk = 0; kk < 64; kk += 32) {
    const int q8 = quad * 8;
    short8 ap = *(const short8*)&Ps[(wid * 16 + l15) * 72 + kk + q8];
#pragma unroll
    for (int nt = 0; nt < 4; ++nt) {
      short8 bv = *(const short8*)&Vt[(nt * 16 + l15) * 72 + kk + q8];
      oacc[nt] = __builtin_amdgcn_mfma_f32_16x16x32_bf16(ap, bv, oacc[nt], 0, 0, 0);
    }
  }
#pragma unroll
  for (int nt = 0; nt < 4; ++nt) {
    int dh = nt * 16 + l15;
#pragma unroll
    for (int r = 0; r < 4; ++r) {
      int t = wid * 16 + quad * 4 + r;
      oattn[((size_t)win * 64 + t) * 512 + head * 64 + dh] = __float2bfloat16(oacc[nt][r]);
    }
  }
}

// ---- GEMM2 + bias + un-patchify scatter ----
__global__ __launch_bounds__(512, 2) void k_gemm_out(const __hip_bfloat16* __restrict__ A,
                                                     const __hip_bfloat16* __restrict__ Bt,
                                                     const float* __restrict__ bias,
                                                     float* __restrict__ out) {
  __shared__ __hip_bfloat16 As[2][256][64];
  __shared__ __hip_bfloat16 Bs[2][256][64];
  const int tid = threadIdx.x;
  const int bid = blockIdx.x;
  const int swz = (bid & 7) * 64 + (bid >> 3);   // 512 blocks
  const int n0 = (swz & 3) * 256, m0 = (swz >> 2) * 256;
  floatx4 acc[8][4] = {};
  gemm256_acc<512>(A, Bt, m0, n0, tid, As, Bs, acc);
  const int lane = tid & 63, wid = tid >> 6;
  const int wm = wid >> 2, wn = wid & 3;
  const int l15 = lane & 15, quad = lane >> 4;
#pragma unroll
  for (int nt = 0; nt < 4; ++nt) {
    const int dp = n0 + wn * 64 + nt * 16 + l15;
    const float bv = bias[dp];
    const int c = dp >> 4, p1 = (dp >> 2) & 3, p2 = dp & 3;
#pragma unroll
    for (int mt = 0; mt < 8; ++mt)
#pragma unroll
      for (int r = 0; r < 4; ++r) {
        const int m = m0 + wm * 128 + mt * 16 + quad * 4 + r;
        const int win = m >> 6, t = m & 63;
        const int i = t >> 3, j = t & 7;
        const int b = win >> 6, h1 = (win >> 3) & 7, w1 = win & 7;
        const int h = h1 * 32 + i * 4 + p1, w = w1 * 32 + j * 4 + p2;
        out[((b * 64 + c) * 256 + h) * 256 + w] = acc[mt][nt][r] + bv;
      }
  }
}

extern "C" void kernel_launch(void* const* d_in, const int* in_sizes, int n_in,
                              void* d_out, int out_size, void* d_ws, size_t ws_size,
                              hipStream_t stream) {
  const float* x    = (const float*)d_in[0];
  const float* wqkv = (const float*)d_in[1];
  const float* wout = (const float*)d_in[2];
  const float* bout = (const float*)d_in[3];
  float* out = (float*)d_out;
  char* ws = (char*)d_ws;
  if (ws_size < WS_NEED) return;

  __hip_bfloat16* tokA  = (__hip_bfloat16*)(ws + OFF_TOKA);
  __hip_bfloat16* oattn = (__hip_bfloat16*)(ws + OFF_TOKA);  // aliases tokA (dead after GEMM1)
  __hip_bfloat16* qkv   = (__hip_bfloat16*)(ws + OFF_QKV);
  __hip_bfloat16* wqT   = (__hip_bfloat16*)(ws + OFF_WQT);
  __hip_bfloat16* woT   = (__hip_bfloat16*)(ws + OFF_WOT);
  float* boP = (float*)(ws + OFF_BO);

  k_perm_wqkv<<<dim3(96, 2), 256, 0, stream>>>(wqkv, wqT);
  k_perm_wout<<<dim3(128, 2), 256, 0, stream>>>(wout, woT);
  k_perm_bias<<<4, 256, 0, stream>>>(bout, boP);
  k_patchify<<<4096, 256, 0, stream>>>(x, tokA);
  k_gemm_qkv<<<512, 512, 0, stream>>>(tokA, wqT, qkv, 2, 0);     // n0 in [0,1024)
  k_gemm_qkv<<<256, 512, 0, stream>>>(tokA, wqT, qkv, 1, 1024);  // n0 in [1024,1536)
  k_attn<<<dim3(512, 8), 256, 0, stream>>>(qkv, oattn);
  k_gemm_out<<<512, 512, 0, stream>>>(oattn, woT, boP, out);
}

// Round 4
// 418.572 us; speedup vs baseline: 1.0625x; 1.0529x over previous
//
#include <hip/hip_runtime.h>
#include <hip/hip_bf16.h>
#include <stdint.h>

typedef __attribute__((ext_vector_type(8))) short short8;
typedef __attribute__((ext_vector_type(4))) float floatx4;

// ---- problem constants ----
constexpr int TD    = 1024;   // token dim
constexpr int E3    = 1536;   // 3*inner
constexpr int INNER = 512;
constexpr int NW    = 512;    // windows
constexpr int M_    = NW * 64; // 32768 tokens

// K-order permutation: reference d = p1*256 + p2*64 + c  <->  d' = c*16 + p1*4 + p2

// ---- workspace layout (bytes) ----
constexpr size_t OFF_TOKA = 0;                                 // tokens bf16 [M, 1024]; oattn aliases later
constexpr size_t OFF_QKV  = (size_t)M_ * TD * 2;               // qkv bf16 [M, 1536]
constexpr size_t OFF_WQT  = OFF_QKV + (size_t)M_ * E3 * 2;     // w_qkv^T bf16 [1536, 1024]
constexpr size_t OFF_WOT  = OFF_WQT + (size_t)E3 * TD * 2;     // w_out^T bf16 [1024, 512]
constexpr size_t OFF_BO   = OFF_WOT + (size_t)TD * INNER * 2;  // bias' fp32 [1024]
constexpr size_t WS_NEED  = OFF_BO + TD * 4;

__device__ __forceinline__ void gl_lds16(const void* g, void* l) {
  __builtin_amdgcn_global_load_lds(
      (const __attribute__((address_space(1))) void*)g,
      (__attribute__((address_space(3))) void*)l, 16, 0, 0);
}

// ---- patchify: x [8,64,256,256] -> tokens bf16 [M, 1024] in d' order ----
__global__ __launch_bounds__(256) void k_patchify(const float* __restrict__ x,
                                                  __hip_bfloat16* __restrict__ tokA) {
  __shared__ __hip_bfloat16 tok[8][1032];
  const int bid = blockIdx.x;
  const int n = bid >> 3, i = bid & 7;
  const int b = n >> 6, h1 = (n >> 3) & 7, w1 = n & 7;
  const int tid = threadIdx.x;
  for (int it = 0; it < 8; ++it) {
    int idx = it * 256 + tid;
    int w4 = idx & 7, p1 = (idx >> 3) & 3, c = idx >> 5;
    int h = h1 * 32 + i * 4 + p1;
    const float4 v = *(const float4*)&x[(((b * 64 + c) * 256 + h) * 256 + w1 * 32 + w4 * 4)];
    __hip_bfloat16* dst = &tok[w4][c * 16 + p1 * 4];
    dst[0] = __float2bfloat16(v.x);
    dst[1] = __float2bfloat16(v.y);
    dst[2] = __float2bfloat16(v.z);
    dst[3] = __float2bfloat16(v.w);
  }
  __syncthreads();
  for (int it = 0; it < 4; ++it) {
    int idx = it * 256 + tid;
    int ch = idx & 127, j = idx >> 7;
    uint4 v = *(const uint4*)&tok[j][ch * 8];
    *(uint4*)&tokA[(size_t)(n * 64 + i * 8 + j) * 1024 + ch * 8] = v;
  }
}

// ---- w_qkv [1024 d][1536 e] fp32 -> wqT bf16 [1536 e][1024 d'] ----
__global__ __launch_bounds__(256) void k_perm_wqkv(const float* __restrict__ wqkv,
                                                   __hip_bfloat16* __restrict__ wqT) {
  __shared__ __hip_bfloat16 wt[16][520];
  const int e0 = blockIdx.x * 16, by = blockIdx.y, tid = threadIdx.x;
  for (int it = 0; it < 32; ++it) {
    int idx = it * 256 + tid;
    int e = idx & 15, dl = idx >> 4;          // dl in [0,512)
    int d = by * 512 + dl;
    float v = wqkv[d * 1536 + e0 + e];
    int c = d & 63, off = (d >> 6) & 7;       // d' = c*16 + by*8 + off
    wt[e][c * 8 + off] = __float2bfloat16(v);
  }
  __syncthreads();
  for (int it = 0; it < 4; ++it) {
    int idx = it * 256 + tid;
    int ch = idx & 63, e = idx >> 6;
    uint4 v = *(const uint4*)&wt[e][ch * 8];
    *(uint4*)&wqT[(size_t)(e0 + e) * 1024 + ch * 16 + by * 8] = v;
  }
}

// ---- w_out [512 e][1024 d] fp32 -> woT bf16 [1024 d'][512 e] ----
__global__ __launch_bounds__(256) void k_perm_wout(const float* __restrict__ wout,
                                                   __hip_bfloat16* __restrict__ woT) {
  __shared__ __hip_bfloat16 wt[4][520];
  const int e0 = blockIdx.x * 4, by = blockIdx.y, tid = threadIdx.x;
  for (int it = 0; it < 8; ++it) {
    int idx = it * 256 + tid;
    int dl = idx & 511, e = idx >> 9;
    int d = by * 512 + dl;
    float v = wout[(e0 + e) * 1024 + d];
    int c = d & 63, off = (d >> 6) & 7;
    wt[e][c * 8 + off] = __float2bfloat16(v);
  }
  __syncthreads();
  for (int it = 0; it < 8; ++it) {
    int idx = it * 256 + tid;
    int e = idx & 3, sl = idx >> 2;           // sl in [0,512)
    int c = sl >> 3, off = sl & 7;
    int dp = c * 16 + by * 8 + off;
    woT[(size_t)dp * 512 + e0 + e] = wt[e][sl];
  }
}

__global__ __launch_bounds__(256) void k_perm_bias(const float* __restrict__ bout,
                                                   float* __restrict__ boP) {
  int dp = blockIdx.x * 256 + threadIdx.x;
  int c = dp >> 4, p1 = (dp >> 2) & 3, p2 = dp & 3;
  boP[dp] = bout[p1 * 256 + p2 * 64 + c];
}

// ============================================================================
// 256x256 GEMM core, ONE BARRIER PER 4-PHASE GROUP (tile = BK=64 = 4 phases).
//   Hazard-derived minimal sync: per group {PH1: bf+afQ1 reads, lgkm4, MFMA Q0,
//   vmcnt(0), s_barrier | PH2..PH4: af prefetch + staged gl_lds, lgkm4, MFMA}.
//   - Staging never targets a region whose reader runs in the same group
//     before the barrier: group t stages Ac1(t+1)->As[p^1], Ac0(t+2)->As[p],
//     B(t+2)->Bs[p] at phases 2-4 only.  (p = t&1)
//   - vmcnt(0) at group start is ~free: youngest outstanding stage is ~2
//     phases (~1600 cyc) old.  It collectivizes (with the barrier) every
//     stage from groups <= t-1; data staged in group g is read >= group g+2
//     phase 1 or later, always after the g+1 barrier.
//   - lgkmcnt(4) per phase leaves only the 4 af-prefetch ds_reads in flight;
//     they drain during the 620-cyc MFMA cluster.
//   - Waves free-run inside a group (role-split: one wave MFMAs while its
//     SIMD-mate stages/reads; setprio arbitrates).
// ============================================================================
template<int K>
__device__ __forceinline__ void gemm256_acc(
    const __hip_bfloat16* __restrict__ A,
    const __hip_bfloat16* __restrict__ Bt,
    int m0, int n0, int tid,
    __hip_bfloat16 (*As)[256][64], __hip_bfloat16 (*Bs)[256][64],
    floatx4 (&acc)[8][4])
{
  const int lane = tid & 63, wid = tid >> 6;
  const int wm = wid >> 2, wn = wid & 3;
  const int l15 = lane & 15, quad = lane >> 4;

  const int rl8 = tid >> 3;
  const int ch0 = (tid & 7) ^ (rl8 & 7);       // pre-swizzled global chunk
  const __hip_bfloat16* Abase = A  + (size_t)(m0 + rl8) * K + ch0 * 8;
  const __hip_bfloat16* Bbase = Bt + (size_t)(n0 + rl8) * K + ch0 * 8;

  // single-load staging quanta (64 rows each)
  auto stB = [&](int tile, int q, int buf) {      // B rows q*64..+64
    gl_lds16(Bbase + (size_t)(q * 64) * K + tile * 64,
             (char*)&Bs[buf][0][0] + q * 8192 + tid * 16);
  };
  auto stA = [&](int tile, int chunk, int j, int buf) {  // A rows j*128+chunk*64..+64
    gl_lds16(Abase + (size_t)(j * 128 + chunk * 64) * K + tile * 64,
             (char*)&As[buf][0][0] + j * 16384 + chunk * 8192 + tid * 16);
  };

  short8 af[2][2][2];   // [set][m2][kh]; set alternates per phase (literal idx)
  short8 bf[4][2];      // [n][kh]; loaded once per group

#define LGKM4 do { asm volatile("s_waitcnt lgkmcnt(4)" ::: "memory"); \
                   __builtin_amdgcn_sched_barrier(0); } while (0)
#define VM0   asm volatile("s_waitcnt vmcnt(0)" ::: "memory")
#define VM6   asm volatile("s_waitcnt vmcnt(6)" ::: "memory")

#define READ_AF(SET, Q, BUF)                                                      \
  do {                                                                            \
    _Pragma("unroll") for (int m2 = 0; m2 < 2; ++m2) {                            \
      const int r = wm * 128 + (2 * (Q) + m2) * 16 + l15;                         \
      _Pragma("unroll") for (int kh = 0; kh < 2; ++kh)                            \
        af[SET][m2][kh] = *(const short8*)&As[BUF][r][((kh * 4 + quad) ^ (r & 7)) * 8]; \
    }                                                                             \
  } while (0)

#define MFMA16(SET, Q)                                                            \
  do {                                                                            \
    __builtin_amdgcn_s_setprio(1);                                                \
    _Pragma("unroll") for (int kh = 0; kh < 2; ++kh)                              \
      _Pragma("unroll") for (int m2 = 0; m2 < 2; ++m2)                            \
        _Pragma("unroll") for (int n = 0; n < 4; ++n)                             \
          acc[2 * (Q) + m2][n] = __builtin_amdgcn_mfma_f32_16x16x32_bf16(         \
              af[SET][m2][kh], bf[n][kh], acc[2 * (Q) + m2][n], 0, 0, 0);         \
    __builtin_amdgcn_s_setprio(0);                                                \
    __builtin_amdgcn_sched_barrier(0);                                            \
  } while (0)

  constexpr int NT = K / 64;

  // ---- prologue: tile0 (B,Ac0,Ac1) + tile1 (B,Ac0); 14 loads
  stB(0, 0, 0); stB(0, 1, 0); stB(0, 2, 0); stB(0, 3, 0);
  stA(0, 0, 0, 0); stA(0, 0, 1, 0);
  stA(0, 1, 0, 0); stA(0, 1, 1, 0);
  stB(1, 0, 1); stB(1, 1, 1); stB(1, 2, 1); stB(1, 3, 1);
  stA(1, 0, 0, 1); stA(1, 0, 1, 1);
  VM6;                                   // drain tile0's 8; leave tile1's 6
  __builtin_amdgcn_s_barrier();
  __builtin_amdgcn_sched_barrier(0);
  READ_AF(0, 0, 0);                      // preload Q0(0); drained by PH1's LGKM4

#define GROUP(P, T)                                                               \
  do {                                                                            \
    /* PH1: bf(T) + afQ1 prefetch; MFMA Q0; group sync */                         \
    _Pragma("unroll") for (int n = 0; n < 4; ++n) {                               \
      const int rb = wn * 64 + n * 16 + l15;                                      \
      _Pragma("unroll") for (int kh = 0; kh < 2; ++kh)                            \
        bf[n][kh] = *(const short8*)&Bs[P][rb][((kh * 4 + quad) ^ (rb & 7)) * 8]; \
    }                                                                             \
    READ_AF(1, 1, P);                                                             \
    LGKM4;                                                                        \
    MFMA16(0, 0);                                                                 \
    VM0;                                                                          \
    __builtin_amdgcn_s_barrier();                                                 \
    __builtin_amdgcn_sched_barrier(0);                                            \
    /* PH2: afQ2 prefetch; stage Ac1(T+1)->As[P^1], Ac0(T+2) part1 */             \
    READ_AF(0, 2, P);                                                             \
    if ((T) + 1 < NT) { stA((T) + 1, 1, 0, (P) ^ 1); stA((T) + 1, 1, 1, (P) ^ 1); } \
    if ((T) + 2 < NT) { stA((T) + 2, 0, 0, P); }                                  \
    LGKM4;                                                                        \
    MFMA16(1, 1);                                                                 \
    /* PH3: afQ3 prefetch; stage Ac0(T+2) part2 + B(T+2) half */                  \
    READ_AF(1, 3, P);                                                             \
    if ((T) + 2 < NT) { stA((T) + 2, 0, 1, P); stB((T) + 2, 0, P); stB((T) + 2, 1, P); } \
    LGKM4;                                                                        \
    MFMA16(0, 2);                                                                 \
    /* PH4: afQ0(T+1) prefetch from As[P^1]; stage B(T+2) half */                 \
    if ((T) + 1 < NT) { READ_AF(0, 0, (P) ^ 1); }                                 \
    if ((T) + 2 < NT) { stB((T) + 2, 2, P); stB((T) + 2, 3, P); }                 \
    LGKM4;                                                                        \
    MFMA16(1, 3);                                                                 \
  } while (0)

#pragma unroll 2
  for (int t = 0; t < NT; ++t) {
    if ((t & 1) == 0) GROUP(0, t); else GROUP(1, t);
  }
#undef GROUP
#undef READ_AF
#undef MFMA16
#undef LGKM4
#undef VM0
#undef VM6
}

// ---- GEMM1: tokens [M,1024] x wqT^T -> qkv bf16 [M,1536] ----
__global__ __launch_bounds__(512, 2) void k_gemm_qkv(const __hip_bfloat16* __restrict__ A,
                                                     const __hip_bfloat16* __restrict__ Bt,
                                                     __hip_bfloat16* __restrict__ Cmat) {
  __shared__ __hip_bfloat16 As[2][256][64];
  __shared__ __hip_bfloat16 Bs[2][256][64];
  const int tid = threadIdx.x;
  const int bid = blockIdx.x;
  const int swz = (bid & 7) * 96 + (bid >> 3);   // 768 blocks, bijective XCD swizzle
  const int n0 = (swz % 6) * 256, m0 = (swz / 6) * 256;  // n-major: A-tile L2 reuse
  floatx4 acc[8][4] = {};
  gemm256_acc<1024>(A, Bt, m0, n0, tid, As, Bs, acc);
  const int lane = tid & 63, wid = tid >> 6;
  const int wm = wid >> 2, wn = wid & 3;
  const int l15 = lane & 15, quad = lane >> 4;
#pragma unroll
  for (int mt = 0; mt < 8; ++mt)
#pragma unroll
    for (int nt = 0; nt < 4; ++nt) {
      const int col = n0 + wn * 64 + nt * 16 + l15;
#pragma unroll
      for (int r = 0; r < 4; ++r) {
        const int row = m0 + wm * 128 + mt * 16 + quad * 4 + r;
        Cmat[(size_t)row * 1536 + col] = __float2bfloat16(acc[mt][nt][r]);
      }
    }
}

// ---- attention: one block per (window, head); swizzled Q/K, bank-clean V transpose ----
__global__ __launch_bounds__(256) void k_attn(const __hip_bfloat16* __restrict__ qkv,
                                              __hip_bfloat16* __restrict__ oattn) {
  __shared__ __hip_bfloat16 Qs[64 * 64];   // [t][dh] swizzled chunks
  __shared__ __hip_bfloat16 Ks[64 * 64];   // [t][dh] swizzled chunks
  __shared__ __hip_bfloat16 Vt[64 * 72];   // [dh][t] padded
  __shared__ __hip_bfloat16 Ps[64 * 72];   // [t][t'] padded; first reused as swizzled Vs[64*64]
  const int win = blockIdx.x, head = blockIdx.y;
  const int tid = threadIdx.x, lane = tid & 63, wid = tid >> 6;
  const int l15 = lane & 15, quad = lane >> 4;
  const int sx = l15 & 7;
  const size_t base = (size_t)win * 64 * 1536 + head * 64;
  for (int l = 0; l < 2; ++l) {
    int idx = l * 256 + tid;
    int t = idx >> 3, ch = idx & 7;
    const size_t rowb = base + (size_t)t * 1536 + ch * 8;
    uint4 q = *(const uint4*)&qkv[rowb];
    uint4 k = *(const uint4*)&qkv[rowb + 512];
    uint4 v = *(const uint4*)&qkv[rowb + 1024];
    const int pos = (ch ^ (t & 7)) * 8;
    *(uint4*)&Qs[t * 64 + pos] = q;
    *(uint4*)&Ks[t * 64 + pos] = k;
    *(uint4*)&Ps[t * 64 + pos] = v;       // Vs staging (swizzled), Ps not yet live
  }
  __syncthreads();
  // transpose V: Vs (swizzled [t][dh]) -> Vt [dh][t]
  {
    const int t = tid & 63, w = tid >> 6;
#pragma unroll
    for (int jn = 0; jn < 2; ++jn) {
      int j = w * 2 + jn;                                  // dh chunk
      short8 v = *(const short8*)&Ps[t * 64 + ((j ^ (t & 7)) * 8)];
#pragma unroll
      for (int jj = 0; jj < 8; ++jj) Vt[(j * 8 + jj) * 72 + t] = ((__hip_bfloat16*)&v)[jj];
    }
  }
  __syncthreads();   // Vs reads done; Ps may now be overwritten by softmax
  // S = Q K^T * scale
  floatx4 sacc[4] = {};
#pragma unroll
  for (int kk = 0; kk < 64; kk += 32) {
    const int pos = (((kk >> 3) + quad) ^ sx) * 8;
    short8 aq = *(const short8*)&Qs[(wid * 16 + l15) * 64 + pos];
#pragma unroll
    for (int ct = 0; ct < 4; ++ct) {
      short8 bk = *(const short8*)&Ks[(ct * 16 + l15) * 64 + pos];
      sacc[ct] = __builtin_amdgcn_mfma_f32_16x16x32_bf16(aq, bk, sacc[ct], 0, 0, 0);
    }
  }
#pragma unroll
  for (int ct = 0; ct < 4; ++ct)
#pragma unroll
    for (int r = 0; r < 4; ++r) sacc[ct][r] = sacc[ct][r] * 0.125f;
  // softmax per row
#pragma unroll
  for (int r = 0; r < 4; ++r) {
    float m = fmaxf(fmaxf(sacc[0][r], sacc[1][r]), fmaxf(sacc[2][r], sacc[3][r]));
    m = fmaxf(m, __shfl_xor(m, 1));
    m = fmaxf(m, __shfl_xor(m, 2));
    m = fmaxf(m, __shfl_xor(m, 4));
    m = fmaxf(m, __shfl_xor(m, 8));
    float ev[4]; float s0 = 0.f;
#pragma unroll
    for (int ct = 0; ct < 4; ++ct) { ev[ct] = __expf(sacc[ct][r] - m); s0 += ev[ct]; }
    s0 += __shfl_xor(s0, 1);
    s0 += __shfl_xor(s0, 2);
    s0 += __shfl_xor(s0, 4);
    s0 += __shfl_xor(s0, 8);
    float inv = 1.0f / s0;
    int row = wid * 16 + quad * 4 + r;
#pragma unroll
    for (int ct = 0; ct < 4; ++ct)
      Ps[row * 72 + ct * 16 + l15] = __float2bfloat16(ev[ct] * inv);
  }
  __syncthreads();
  // O = P V
  floatx4 oacc[4] = {};
#pragma unroll
  for (int kk = 0; kk < 64; kk += 32) {
    const int q8 = quad * 8;
    short8 ap = *(const short8*)&Ps[(wid * 16 + l15) * 72 + kk + q8];
#pragma unroll
    for (int nt = 0; nt < 4; ++nt) {
      short8 bv = *(const short8*)&Vt[(nt * 16 + l15) * 72 + kk + q8];
      oacc[nt] = __builtin_amdgcn_mfma_f32_16x16x32_bf16(ap, bv, oacc[nt], 0, 0, 0);
    }
  }
#pragma unroll
  for (int nt = 0; nt < 4; ++nt) {
    int dh = nt * 16 + l15;
#pragma unroll
    for (int r = 0; r < 4; ++r) {
      int t = wid * 16 + quad * 4 + r;
      oattn[((size_t)win * 64 + t) * 512 + head * 64 + dh] = __float2bfloat16(oacc[nt][r]);
    }
  }
}

// ---- GEMM2 + bias + un-patchify scatter ----
__global__ __launch_bounds__(512, 2) void k_gemm_out(const __hip_bfloat16* __restrict__ A,
                                                     const __hip_bfloat16* __restrict__ Bt,
                                                     const float* __restrict__ bias,
                                                     float* __restrict__ out) {
  __shared__ __hip_bfloat16 As[2][256][64];
  __shared__ __hip_bfloat16 Bs[2][256][64];
  const int tid = threadIdx.x;
  const int bid = blockIdx.x;
  const int swz = (bid & 7) * 64 + (bid >> 3);   // 512 blocks
  const int n0 = (swz & 3) * 256, m0 = (swz >> 2) * 256;
  floatx4 acc[8][4] = {};
  gemm256_acc<512>(A, Bt, m0, n0, tid, As, Bs, acc);
  const int lane = tid & 63, wid = tid >> 6;
  const int wm = wid >> 2, wn = wid & 3;
  const int l15 = lane & 15, quad = lane >> 4;
#pragma unroll
  for (int nt = 0; nt < 4; ++nt) {
    const int dp = n0 + wn * 64 + nt * 16 + l15;
    const float bv = bias[dp];
    const int c = dp >> 4, p1 = (dp >> 2) & 3, p2 = dp & 3;
#pragma unroll
    for (int mt = 0; mt < 8; ++mt)
#pragma unroll
      for (int r = 0; r < 4; ++r) {
        const int m = m0 + wm * 128 + mt * 16 + quad * 4 + r;
        const int win = m >> 6, t = m & 63;
        const int i = t >> 3, j = t & 7;
        const int b = win >> 6, h1 = (win >> 3) & 7, w1 = win & 7;
        const int h = h1 * 32 + i * 4 + p1, w = w1 * 32 + j * 4 + p2;
        out[((b * 64 + c) * 256 + h) * 256 + w] = acc[mt][nt][r] + bv;
      }
  }
}

extern "C" void kernel_launch(void* const* d_in, const int* in_sizes, int n_in,
                              void* d_out, int out_size, void* d_ws, size_t ws_size,
                              hipStream_t stream) {
  const float* x    = (const float*)d_in[0];
  const float* wqkv = (const float*)d_in[1];
  const float* wout = (const float*)d_in[2];
  const float* bout = (const float*)d_in[3];
  float* out = (float*)d_out;
  char* ws = (char*)d_ws;
  if (ws_size < WS_NEED) return;

  __hip_bfloat16* tokA  = (__hip_bfloat16*)(ws + OFF_TOKA);
  __hip_bfloat16* oattn = (__hip_bfloat16*)(ws + OFF_TOKA);  // aliases tokA (dead after GEMM1)
  __hip_bfloat16* qkv   = (__hip_bfloat16*)(ws + OFF_QKV);
  __hip_bfloat16* wqT   = (__hip_bfloat16*)(ws + OFF_WQT);
  __hip_bfloat16* woT   = (__hip_bfloat16*)(ws + OFF_WOT);
  float* boP = (float*)(ws + OFF_BO);

  k_perm_wqkv<<<dim3(96, 2), 256, 0, stream>>>(wqkv, wqT);
  k_perm_wout<<<dim3(128, 2), 256, 0, stream>>>(wout, woT);
  k_perm_bias<<<4, 256, 0, stream>>>(bout, boP);
  k_patchify<<<4096, 256, 0, stream>>>(x, tokA);
  k_gemm_qkv<<<768, 512, 0, stream>>>(tokA, wqT, qkv);
  k_attn<<<dim3(512, 8), 256, 0, stream>>>(qkv, oattn);
  k_gemm_out<<<512, 512, 0, stream>>>(oattn, woT, boP, out);
}